// Round 7
// baseline (2264.012 us; speedup 1.0000x reference)
//
#include <hip/hip_runtime.h>
#include <hip/hip_bf16.h>

#define NIN    512
#define NEVAL  1536
#define NCOLS  2048
#define NOUT   256
#define OUT_BASE 1280
#define BK     64
#define NBLK   24        // NEVAL / BK
#define NROWS  16        // batch rows per WG
#define WDS    68        // Wd col stride (floats): 16B-aligned, uniform b128 reads
#define ZSTR   68        // Zc row stride (floats)

typedef __attribute__((ext_vector_type(8))) short short8;   // 8 bf16 (4 VGPRs)
typedef __attribute__((ext_vector_type(4))) float floatx4;  // MFMA C/D

#define C5 (-7.21347520444481703f)   // -5*log2(e): sigmoid(5z) = rcp(1+exp2(C5*z))

// ---------- helpers ----------

__device__ __forceinline__ unsigned short f2bf(float f) {
    __hip_bfloat16 h = __float2bfloat16(f);
    return __builtin_bit_cast(unsigned short, h);
}
__device__ __forceinline__ unsigned pack2(float a, float b) {
    return (unsigned)f2bf(a) | ((unsigned)f2bf(b) << 16);
}
// sigmoid in folded domain: y = C5*(z+b); sigma = rcp(1+exp2(y)). Overflow exact.
__device__ __forceinline__ float sig2(float y) {
    return __builtin_amdgcn_rcpf(1.0f + __builtin_amdgcn_exp2f(y));
}

// ---------- W fp32 -> bf16 (d_ws re-poisoned every launch, so rerun) ----------
// Workspace usage is EXACTLY NEVAL*NCOLS*2 bytes (proven safe).

__global__ __launch_bounds__(256) void wconv(const float* __restrict__ W,
                                             ushort* __restrict__ Wb, int n8) {
    int i = blockIdx.x * blockDim.x + threadIdx.x;
    if (i < n8) {
        float4 v0 = ((const float4*)W)[2 * i];
        float4 v1 = ((const float4*)W)[2 * i + 1];
        uint4 pk;
        pk.x = pack2(v0.x, v0.y); pk.y = pack2(v0.z, v0.w);
        pk.z = pack2(v1.x, v1.y); pk.w = pack2(v1.z, v1.w);
        ((uint4*)Wb)[i] = pk;
    }
}

// ---------- main kernel ----------
// ROUND-19: R17/R18 structure; chain y[] moved from (scratch-demoted) array
// to 16 NAMED floatx4 registers with macro-generated literal-index steps.
// Evidence: R18 removed the VGPR cap (512,1) yet VGPR stayed 124 and
// WRITE_SIZE stayed +4.1MB -> y[64] was in scratch via rule-20 (runtime-
// indexed array), not register pressure. Triangle guards are constant-
// folded (quad q updated iff q*4+3 > J); elements i<=J ride along with
// exactly-zero staged weights (strict lower-tri in memory) -> bit-identical.
//   role 0      (1 wave): chain, lane=row (lanes 0..15 real). vy0..vy15 in
//               VGPRs; 1 exp2+rcp per step serves all 16 rows; no readlane;
//               weights = uniform ds_read_b128 broadcast from Wd.
//   roles 1,2,3,5 (4 waves): mains, node-group ng. Phase 1: tail(k) = 2
//               MFMAs (B prefetched) + Zc^T store. Phase 2: main(k+1) over
//               [0,512+64k) into regs + prefetch tail B(k+1).
//   roles 4,6,7 (3 waves): stagers: Wd[(k+1)&1][j*WDS+i] =
//               C5*W[64(k+1)+i][512+64(k+1)+j] (16KB, coalesced).
// Slot: phase1 | beta | phase2 | alpha. Disjoint: mains read O cols
// [0,512+64k); chain writes [512+64k,+64).

// --- chain macros: all indices are LITERALS -> registers, never scratch ---
#define UPD(q, J, o) \
    if ((q) * 4 + 3 > (J)) { \
        floatx4 wv = *(const floatx4*)(wc + (q) * 4); \
        vy##q = wv * (o) + vy##q; \
    }
#define UPDALL(J, o) \
    UPD(0,J,o)  UPD(1,J,o)  UPD(2,J,o)  UPD(3,J,o) \
    UPD(4,J,o)  UPD(5,J,o)  UPD(6,J,o)  UPD(7,J,o) \
    UPD(8,J,o)  UPD(9,J,o)  UPD(10,J,o) UPD(11,J,o) \
    UPD(12,J,o) UPD(13,J,o) UPD(14,J,o) UPD(15,J,o)
#define STEP(J, VQ, C, ON) { \
    ON = sig2(vy##VQ.C); \
    const float* wc = wd + (J) * WDS; \
    UPDALL(J, ON) \
}
#define STORE_GROUP(g) \
    if (lane < NROWS) { \
        uint4 pk; \
        pk.x = pack2(o0, o1); pk.y = pack2(o2, o3); \
        pk.z = pack2(o4, o5); pk.w = pack2(o6, o7); \
        *(uint4*)&O[(rr << 11) + ((L0 + (g) * 8 + (rr << 3)) & 2047)] = pk; \
        if (k >= 20) { \
            float* op = out + ((long)blockIdx.x * NROWS + rr) * NOUT \
                            + (i0 - OUT_BASE) + (g) * 8; \
            *(float4*)op       = float4{o0, o1, o2, o3}; \
            *(float4*)(op + 4) = float4{o4, o5, o6, o7}; \
        } \
    }
#define INITQ(q) { \
    floatx4 zv = *(const floatx4*)(zr + (q) * 4); \
    floatx4 bv = { bb[(q)*4], bb[(q)*4+1], bb[(q)*4+2], bb[(q)*4+3] }; \
    vy##q = (zv + bv) * C5; \
}

__global__ __launch_bounds__(512, 1) void ffnet(const float* __restrict__ x,
                                                const float* __restrict__ W,
                                                const ushort* __restrict__ Wb,
                                                const float* __restrict__ bias,
                                                float* __restrict__ out) {
    __shared__ unsigned short O[NROWS * 2048];   // 64 KB
    __shared__ float Wd[2][64 * WDS];            // 34.8 KB dbuf diag blocks [j][i]
    __shared__ float Zc[NROWS * ZSTR];           // 4.4 KB  [row][node]

    const int t    = threadIdx.x;
    const int w    = t >> 6;        // wave 0..7
    const int lane = t & 63;

    const int cw   = (int)blockIdx.x & 7;
    const int role = (w - cw) & 7;
    const bool isMain   = (role == 1) | (role == 2) | (role == 3) | (role == 5);
    const bool isStager = (role == 4) | (role == 6) | (role == 7);
    const int ng   = (role >= 5) ? 3 : role - 1;              // valid iff isMain
    const int sidx = (role == 4) ? 0 : ((role == 6) ? 1 : 2); // valid iff isStager
    const int spt  = (sidx << 6) + lane;                      // 0..191

    // MFMA frag roles (mains)
    const int m16  = lane & 15;     // A row (batch row) / D col (node in group)
    const int quad = lane >> 4;
    const int arow = m16 << 11;
    const int arot = m16 << 3;

    // chain role: lane rr = batch row (lanes 16..63 duplicate, stores masked)
    const int rr   = lane & 15;

    // ---- stage x rows into LDS as bf16 (swizzled); 8 waves x 2 rows ----
    #pragma unroll
    for (int r2 = 0; r2 < 2; ++r2) {
        const int rs = w + (r2 << 3);
        const long rowS = (long)blockIdx.x * NROWS + rs;
        const float* xr = x + rowS * NIN + lane * 8;
        float4 v0 = *(const float4*)xr;
        float4 v1 = *(const float4*)(xr + 4);
        uint4 pk;
        pk.x = pack2(v0.x, v0.y); pk.y = pack2(v0.z, v0.w);
        pk.z = pack2(v1.x, v1.y); pk.w = pack2(v1.z, v1.w);
        *(uint4*)&O[(rs << 11) + ((lane * 8 + (rs << 3)) & 2047)] = pk;
    }
    __syncthreads();

    short8 tb0 = {}, tb1 = {};      // prefetched tail B-frags
    floatx4 accM = {0.f, 0.f, 0.f, 0.f};

    // ---- prologue (phase-2-like work for slot 0) ----
    if (isMain) {
        const ushort* wbr = Wb + (size_t)((ng << 4) + m16) * NCOLS;
        #pragma unroll 4
        for (int kk = 0; kk < NIN - BK; kk += 32) {
            short8 a = *(const short8*)&O[arow + ((kk + (quad << 3) + arot) & 2047)];
            short8 b = *(const short8*)&wbr[kk + (quad << 3)];
            accM = __builtin_amdgcn_mfma_f32_16x16x32_bf16(a, b, accM, 0, 0, 0);
        }
        tb0 = *(const short8*)&wbr[(NIN - BK) + (quad << 3)];
        tb1 = *(const short8*)&wbr[(NIN - 32) + (quad << 3)];
    } else if (isStager) {
        // stage Wd[0] for block 0: Wd[j*WDS+i] = C5*W[i][512+j]
        const float* wsrc = W + NIN;
        for (int idx = spt; idx < 4096; idx += 192) {
            const int i = idx >> 6, j = idx & 63;
            Wd[0][j * WDS + i] = C5 * wsrc[(size_t)i * NCOLS + j];
        }
    }

    for (int k = 0; k < NBLK; ++k) {
        const int i0 = k << 6;
        const int L0 = NIN + i0;

        // ===== phase 1: mains: tail(k) + Zc^T store =====
        if (isMain) {
            const int ts = L0 - BK;
            short8 a0 = *(const short8*)&O[arow + ((ts + (quad << 3) + arot) & 2047)];
            accM = __builtin_amdgcn_mfma_f32_16x16x32_bf16(a0, tb0, accM, 0, 0, 0);
            short8 a1 = *(const short8*)&O[arow + ((ts + 32 + (quad << 3) + arot) & 2047)];
            accM = __builtin_amdgcn_mfma_f32_16x16x32_bf16(a1, tb1, accM, 0, 0, 0);
            // D: lane q*16+n holds z[row 4q+p][node 16ng+n]
            const int n = (ng << 4) + m16;
            #pragma unroll
            for (int p = 0; p < 4; ++p)
                Zc[((quad << 2) + p) * ZSTR + n] = accM[p];
        }
        __syncthreads();            // beta: Zc(k) + Wd(k) visible

        if (role == 0) {
            // ===== chain: block k, lane=row, 64 static steps =====
            floatx4 vy0, vy1, vy2, vy3, vy4, vy5, vy6, vy7;
            floatx4 vy8, vy9, vy10, vy11, vy12, vy13, vy14, vy15;
            {
                const float* zr = &Zc[rr * ZSTR];
                const float* bb = bias + i0;    // uniform -> s_load
                INITQ(0)  INITQ(1)  INITQ(2)  INITQ(3)
                INITQ(4)  INITQ(5)  INITQ(6)  INITQ(7)
                INITQ(8)  INITQ(9)  INITQ(10) INITQ(11)
                INITQ(12) INITQ(13) INITQ(14) INITQ(15)
            }
            const float* wd = &Wd[k & 1][0];
            float o0, o1, o2, o3, o4, o5, o6, o7;

            STEP(0,0,x,o0)   STEP(1,0,y,o1)   STEP(2,0,z,o2)   STEP(3,0,w,o3)
            STEP(4,1,x,o4)   STEP(5,1,y,o5)   STEP(6,1,z,o6)   STEP(7,1,w,o7)
            STORE_GROUP(0)
            STEP(8,2,x,o0)   STEP(9,2,y,o1)   STEP(10,2,z,o2)  STEP(11,2,w,o3)
            STEP(12,3,x,o4)  STEP(13,3,y,o5)  STEP(14,3,z,o6)  STEP(15,3,w,o7)
            STORE_GROUP(1)
            STEP(16,4,x,o0)  STEP(17,4,y,o1)  STEP(18,4,z,o2)  STEP(19,4,w,o3)
            STEP(20,5,x,o4)  STEP(21,5,y,o5)  STEP(22,5,z,o6)  STEP(23,5,w,o7)
            STORE_GROUP(2)
            STEP(24,6,x,o0)  STEP(25,6,y,o1)  STEP(26,6,z,o2)  STEP(27,6,w,o3)
            STEP(28,7,x,o4)  STEP(29,7,y,o5)  STEP(30,7,z,o6)  STEP(31,7,w,o7)
            STORE_GROUP(3)
            STEP(32,8,x,o0)  STEP(33,8,y,o1)  STEP(34,8,z,o2)  STEP(35,8,w,o3)
            STEP(36,9,x,o4)  STEP(37,9,y,o5)  STEP(38,9,z,o6)  STEP(39,9,w,o7)
            STORE_GROUP(4)
            STEP(40,10,x,o0) STEP(41,10,y,o1) STEP(42,10,z,o2) STEP(43,10,w,o3)
            STEP(44,11,x,o4) STEP(45,11,y,o5) STEP(46,11,z,o6) STEP(47,11,w,o7)
            STORE_GROUP(5)
            STEP(48,12,x,o0) STEP(49,12,y,o1) STEP(50,12,z,o2) STEP(51,12,w,o3)
            STEP(52,13,x,o4) STEP(53,13,y,o5) STEP(54,13,z,o6) STEP(55,13,w,o7)
            STORE_GROUP(6)
            STEP(56,14,x,o0) STEP(57,14,y,o1) STEP(58,14,z,o2) STEP(59,14,w,o3)
            STEP(60,15,x,o4) STEP(61,15,y,o5) STEP(62,15,z,o6) STEP(63,15,w,o7)
            STORE_GROUP(7)
        } else if (isMain && k + 1 < NBLK) {
            // ===== mains: main(k+1) over [0, 512+64k) + tail-B prefetch =====
            const int b = k + 1;
            const ushort* wbr = Wb + (size_t)((b << 6) + (ng << 4) + m16) * NCOLS;
            const int ts = NIN + (b << 6) - BK;
            tb0 = *(const short8*)&wbr[ts + (quad << 3)];
            tb1 = *(const short8*)&wbr[ts + 32 + (quad << 3)];
            floatx4 z = {0.f, 0.f, 0.f, 0.f};
            const int hi = NIN + i0;
            #pragma unroll 4
            for (int kk = 0; kk < hi; kk += 32) {
                short8 a  = *(const short8*)&O[arow + ((kk + (quad << 3) + arot) & 2047)];
                short8 bf = *(const short8*)&wbr[kk + (quad << 3)];
                z = __builtin_amdgcn_mfma_f32_16x16x32_bf16(a, bf, z, 0, 0, 0);
            }
            accM = z;
        } else if (isStager && k + 1 < NBLK) {
            // ===== stagers: Wd[(k+1)&1] = C5 * diag-block(k+1), transposed =====
            const int b = k + 1;
            float* wdn = &Wd[b & 1][0];
            const float* wsrc = W + (size_t)(b << 6) * NCOLS + (NIN + (b << 6));
            for (int idx = spt; idx < 4096; idx += 192) {
                const int i = idx >> 6, j = idx & 63;
                wdn[j * WDS + i] = C5 * wsrc[(size_t)i * NCOLS + j];
            }
        }
        __syncthreads();            // alpha: O(k) visible; Zc/Wd consumed
    }
}

// ---------- launch ----------

extern "C" void kernel_launch(void* const* d_in, const int* in_sizes, int n_in,
                              void* d_out, int out_size, void* d_ws, size_t ws_size,
                              hipStream_t stream) {
    const float* x  = (const float*)d_in[0];   // [4096, 512]
    const float* W  = (const float*)d_in[1];   // [1536, 2048]
    const float* b  = (const float*)d_in[2];   // [1536]
    float* out = (float*)d_out;                // [4096, 256]
    ushort* Wb = (ushort*)d_ws;                // bf16 W copy (6.29 MB, exact proven usage)

    int n8 = NEVAL * NCOLS / 8;
    wconv<<<n8 / 256, 256, 0, stream>>>(W, Wb, n8);
    ffnet<<<4096 / NROWS, 512, 0, stream>>>(x, W, Wb, b, out);
}

// Round 8
// 247.702 us; speedup vs baseline: 9.1401x; 9.1401x over previous
//
#include <hip/hip_runtime.h>
#include <hip/hip_bf16.h>

#define NIN    512
#define NEVAL  1536
#define NCOLS  2048
#define NOUT   256
#define OUT_BASE 1280
#define BK     64
#define NBLK   24        // NEVAL / BK
#define NROWS  16        // batch rows per WG
#define WDS    68        // Wd col stride (floats): 16B-aligned
#define ZSTR   68        // Zc row stride (floats)

typedef __attribute__((ext_vector_type(8))) short short8;   // 8 bf16 (4 VGPRs)
typedef __attribute__((ext_vector_type(4))) float floatx4;  // MFMA C/D

#define C5 (-7.21347520444481703f)   // -5*log2(e): sigmoid(5z) = rcp(1+exp2(C5*z))

// ---------- helpers ----------

__device__ __forceinline__ unsigned short f2bf(float f) {
    __hip_bfloat16 h = __float2bfloat16(f);
    return __builtin_bit_cast(unsigned short, h);
}
__device__ __forceinline__ unsigned pack2(float a, float b) {
    return (unsigned)f2bf(a) | ((unsigned)f2bf(b) << 16);
}
// sigmoid in folded domain: y = C5*(z+b); sigma = rcp(1+exp2(y)). Overflow exact.
__device__ __forceinline__ float sig2(float y) {
    return __builtin_amdgcn_rcpf(1.0f + __builtin_amdgcn_exp2f(y));
}

// ---------- W fp32 -> bf16 (d_ws re-poisoned every launch, so rerun) ----------
// Workspace usage is EXACTLY NEVAL*NCOLS*2 bytes (proven safe).

__global__ __launch_bounds__(256) void wconv(const float* __restrict__ W,
                                             ushort* __restrict__ Wb, int n8) {
    int i = blockIdx.x * blockDim.x + threadIdx.x;
    if (i < n8) {
        float4 v0 = ((const float4*)W)[2 * i];
        float4 v1 = ((const float4*)W)[2 * i + 1];
        uint4 pk;
        pk.x = pack2(v0.x, v0.y); pk.y = pack2(v0.z, v0.w);
        pk.z = pack2(v1.x, v1.y); pk.w = pack2(v1.z, v1.w);
        ((uint4*)Wb)[i] = pk;
    }
}

// ---------- main kernel ----------
// ROUND-20: chain state distributed across lane groups. R17-R19 all pinned
// VGPR at 124-128 with scratch spill (R19: 2GB/dispatch writes) -> the
// allocator caps this kernel at 128 VGPRs regardless of launch bounds; a
// 64-float-per-lane chain cannot fit. Fix by construction: lane 16g+r holds
// y[16g..16g+15][row r] -> vy = 4 floatx4 = 16 VGPRs. Per step J (literal):
//   - all lanes sig2 their local elem (owner group J>>4 yields real o_J[r])
//   - ds_bpermute broadcasts o_J[r] from owner lanes to all lanes
//   - 4 UNGUARDED quad-fmas: weights for i<=J are exactly 0.0 in W (strict
//     lower tri) -> ride-along is bit-exact; no divergence; 16 fma/step.
// Weight col reads: 4x ds_read_b128, 4 distinct addrs/wave (per group).
//   role 0      (1 wave): chain (above).
//   roles 1,2,3,5 (4 waves): mains, node-group ng. Phase 1: tail(k) = 2
//               MFMAs (B prefetched) + Zc^T store. Phase 2: main(k+1) over
//               [0,512+64k) into regs + prefetch tail B(k+1).
//   roles 4,6,7 (3 waves): stagers: Wd[(k+1)&1][j*WDS+i] =
//               C5... (NO C5 here: chain folds C5 at init; Wd holds raw W?
//               -> Wd must be PRE-SCALED by C5 so fma accumulates in folded
//               domain; stagers scale as before.)
// Slot: phase1 | beta | phase2 | alpha. Disjoint: mains read O cols
// [0,512+64k); chain writes [512+64k,+64).

// --- chain macros: literal indices only ---
#define CSTEP(J, Q, C, ON) { \
    float sg_ = sig2(vq##Q.C); \
    ON = __builtin_bit_cast(float, \
        __builtin_amdgcn_ds_bpermute(bpaddr + (((J) >> 4) << 6), \
                                     __builtin_bit_cast(int, sg_))); \
    const float* wc_ = wd + (J) * WDS + g16; \
    floatx4 w0_ = *(const floatx4*)(wc_); \
    floatx4 w1_ = *(const floatx4*)(wc_ + 4); \
    floatx4 w2_ = *(const floatx4*)(wc_ + 8); \
    floatx4 w3_ = *(const floatx4*)(wc_ + 12); \
    vq0 = w0_ * ON + vq0; \
    vq1 = w1_ * ON + vq1; \
    vq2 = w2_ * ON + vq2; \
    vq3 = w3_ * ON + vq3; \
}
#define CSTORE(gidx) \
    if (lane < 16) { \
        uint4 pk; \
        pk.x = pack2(o0, o1); pk.y = pack2(o2, o3); \
        pk.z = pack2(o4, o5); pk.w = pack2(o6, o7); \
        *(uint4*)&O[(rr << 11) + ((L0 + (gidx) * 8 + (rr << 3)) & 2047)] = pk; \
        if (k >= 20) { \
            float* op = out + ((long)blockIdx.x * NROWS + rr) * NOUT \
                            + (i0 - OUT_BASE) + (gidx) * 8; \
            *(float4*)op       = float4{o0, o1, o2, o3}; \
            *(float4*)(op + 4) = float4{o4, o5, o6, o7}; \
        } \
    }
#define CINIT(Q) { \
    floatx4 zv_ = *(const floatx4*)(zr + (Q) * 4); \
    float4  bv_ = *(const float4*)(bb + (Q) * 4); \
    vq##Q.x = C5 * (zv_.x + bv_.x); \
    vq##Q.y = C5 * (zv_.y + bv_.y); \
    vq##Q.z = C5 * (zv_.z + bv_.z); \
    vq##Q.w = C5 * (zv_.w + bv_.w); \
}
// 16 steps of one leaf pair + stores (pattern repeats every 16 steps)
#define CLEAF(B) \
    CSTEP((B)+0,0,x,o0)  CSTEP((B)+1,0,y,o1)  CSTEP((B)+2,0,z,o2)  CSTEP((B)+3,0,w,o3) \
    CSTEP((B)+4,1,x,o4)  CSTEP((B)+5,1,y,o5)  CSTEP((B)+6,1,z,o6)  CSTEP((B)+7,1,w,o7) \
    CSTORE((B)/8) \
    CSTEP((B)+8,2,x,o0)  CSTEP((B)+9,2,y,o1)  CSTEP((B)+10,2,z,o2) CSTEP((B)+11,2,w,o3) \
    CSTEP((B)+12,3,x,o4) CSTEP((B)+13,3,y,o5) CSTEP((B)+14,3,z,o6) CSTEP((B)+15,3,w,o7) \
    CSTORE((B)/8 + 1)

__global__ __launch_bounds__(512, 1) void ffnet(const float* __restrict__ x,
                                                const float* __restrict__ W,
                                                const ushort* __restrict__ Wb,
                                                const float* __restrict__ bias,
                                                float* __restrict__ out) {
    __shared__ unsigned short O[NROWS * 2048];   // 64 KB
    __shared__ float Wd[2][64 * WDS];            // 34.8 KB dbuf diag blocks [j][i], C5-scaled
    __shared__ float Zc[NROWS * ZSTR];           // 4.4 KB  [row][node]

    const int t    = threadIdx.x;
    const int w    = t >> 6;        // wave 0..7
    const int lane = t & 63;

    const int cw   = (int)blockIdx.x & 7;
    const int role = (w - cw) & 7;
    const bool isMain   = (role == 1) | (role == 2) | (role == 3) | (role == 5);
    const bool isStager = (role == 4) | (role == 6) | (role == 7);
    const int ng   = (role >= 5) ? 3 : role - 1;              // valid iff isMain
    const int sidx = (role == 4) ? 0 : ((role == 6) ? 1 : 2); // valid iff isStager
    const int spt  = (sidx << 6) + lane;                      // 0..191

    // MFMA frag roles (mains)
    const int m16  = lane & 15;     // A row (batch row) / D col (node in group)
    const int quad = lane >> 4;
    const int arow = m16 << 11;
    const int arot = m16 << 3;

    // chain roles: lane = 16g + r
    const int rr     = lane & 15;          // batch row
    const int g16    = (lane >> 4) << 4;   // node-group base (0,16,32,48)
    const int bpaddr = rr << 2;            // bpermute byte base (src lane r)

    // ---- stage x rows into LDS as bf16 (swizzled); 8 waves x 2 rows ----
    #pragma unroll
    for (int r2 = 0; r2 < 2; ++r2) {
        const int rs = w + (r2 << 3);
        const long rowS = (long)blockIdx.x * NROWS + rs;
        const float* xr = x + rowS * NIN + lane * 8;
        float4 v0 = *(const float4*)xr;
        float4 v1 = *(const float4*)(xr + 4);
        uint4 pk;
        pk.x = pack2(v0.x, v0.y); pk.y = pack2(v0.z, v0.w);
        pk.z = pack2(v1.x, v1.y); pk.w = pack2(v1.z, v1.w);
        *(uint4*)&O[(rs << 11) + ((lane * 8 + (rs << 3)) & 2047)] = pk;
    }
    __syncthreads();

    short8 tb0 = {}, tb1 = {};      // prefetched tail B-frags
    floatx4 accM = {0.f, 0.f, 0.f, 0.f};

    // ---- prologue (phase-2-like work for slot 0) ----
    if (isMain) {
        const ushort* wbr = Wb + (size_t)((ng << 4) + m16) * NCOLS;
        #pragma unroll 4
        for (int kk = 0; kk < NIN - BK; kk += 32) {
            short8 a = *(const short8*)&O[arow + ((kk + (quad << 3) + arot) & 2047)];
            short8 b = *(const short8*)&wbr[kk + (quad << 3)];
            accM = __builtin_amdgcn_mfma_f32_16x16x32_bf16(a, b, accM, 0, 0, 0);
        }
        tb0 = *(const short8*)&wbr[(NIN - BK) + (quad << 3)];
        tb1 = *(const short8*)&wbr[(NIN - 32) + (quad << 3)];
    } else if (isStager) {
        // stage Wd[0] for block 0: Wd[j*WDS+i] = C5*W[i][512+j]
        const float* wsrc = W + NIN;
        for (int idx = spt; idx < 4096; idx += 192) {
            const int i = idx >> 6, j = idx & 63;
            Wd[0][j * WDS + i] = C5 * wsrc[(size_t)i * NCOLS + j];
        }
    }

    for (int k = 0; k < NBLK; ++k) {
        const int i0 = k << 6;
        const int L0 = NIN + i0;

        // ===== phase 1: mains: tail(k) + Zc^T store =====
        if (isMain) {
            const int ts = L0 - BK;
            short8 a0 = *(const short8*)&O[arow + ((ts + (quad << 3) + arot) & 2047)];
            accM = __builtin_amdgcn_mfma_f32_16x16x32_bf16(a0, tb0, accM, 0, 0, 0);
            short8 a1 = *(const short8*)&O[arow + ((ts + 32 + (quad << 3) + arot) & 2047)];
            accM = __builtin_amdgcn_mfma_f32_16x16x32_bf16(a1, tb1, accM, 0, 0, 0);
            // D: lane q*16+n holds z[row 4q+p][node 16ng+n]
            const int n = (ng << 4) + m16;
            #pragma unroll
            for (int p = 0; p < 4; ++p)
                Zc[((quad << 2) + p) * ZSTR + n] = accM[p];
        }
        __syncthreads();            // beta: Zc(k) + Wd(k) visible

        if (role == 0) {
            // ===== chain: block k, 64 static steps, state in 4 quads =====
            floatx4 vq0, vq1, vq2, vq3;
            {
                const float* zr = &Zc[rr * ZSTR + g16];
                const float* bb = bias + i0 + g16;
                CINIT(0) CINIT(1) CINIT(2) CINIT(3)
            }
            const float* wd = &Wd[k & 1][0];
            float o0, o1, o2, o3, o4, o5, o6, o7;
            CLEAF(0)
            CLEAF(16)
            CLEAF(32)
            CLEAF(48)
        } else if (isMain && k + 1 < NBLK) {
            // ===== mains: main(k+1) over [0, 512+64k) + tail-B prefetch =====
            const int b = k + 1;
            const ushort* wbr = Wb + (size_t)((b << 6) + (ng << 4) + m16) * NCOLS;
            const int ts = NIN + (b << 6) - BK;
            tb0 = *(const short8*)&wbr[ts + (quad << 3)];
            tb1 = *(const short8*)&wbr[ts + 32 + (quad << 3)];
            floatx4 z = {0.f, 0.f, 0.f, 0.f};
            const int hi = NIN + i0;
            #pragma unroll 4
            for (int kk = 0; kk < hi; kk += 32) {
                short8 a  = *(const short8*)&O[arow + ((kk + (quad << 3) + arot) & 2047)];
                short8 bf = *(const short8*)&wbr[kk + (quad << 3)];
                z = __builtin_amdgcn_mfma_f32_16x16x32_bf16(a, bf, z, 0, 0, 0);
            }
            accM = z;
        } else if (isStager && k + 1 < NBLK) {
            // ===== stagers: Wd[(k+1)&1] = C5 * diag-block(k+1), transposed =====
            const int b = k + 1;
            float* wdn = &Wd[b & 1][0];
            const float* wsrc = W + (size_t)(b << 6) * NCOLS + (NIN + (b << 6));
            for (int idx = spt; idx < 4096; idx += 192) {
                const int i = idx >> 6, j = idx & 63;
                wdn[j * WDS + i] = C5 * wsrc[(size_t)i * NCOLS + j];
            }
        }
        __syncthreads();            // alpha: O(k) visible; Zc/Wd consumed
    }
}

// ---------- launch ----------

extern "C" void kernel_launch(void* const* d_in, const int* in_sizes, int n_in,
                              void* d_out, int out_size, void* d_ws, size_t ws_size,
                              hipStream_t stream) {
    const float* x  = (const float*)d_in[0];   // [4096, 512]
    const float* W  = (const float*)d_in[1];   // [1536, 2048]
    const float* b  = (const float*)d_in[2];   // [1536]
    float* out = (float*)d_out;                // [4096, 256]
    ushort* Wb = (ushort*)d_ws;                // bf16 W copy (6.29 MB, exact proven usage)

    int n8 = NEVAL * NCOLS / 8;
    wconv<<<n8 / 256, 256, 0, stream>>>(W, Wb, n8);
    ffnet<<<4096 / NROWS, 512, 0, stream>>>(x, W, Wb, b, out);
}

// Round 9
// 244.721 us; speedup vs baseline: 9.2514x; 1.0122x over previous
//
#include <hip/hip_runtime.h>
#include <hip/hip_bf16.h>

#define NIN    512
#define NEVAL  1536
#define NCOLS  2048
#define NOUT   256
#define OUT_BASE 1280
#define BK     64
#define NBLK   24        // NEVAL / BK
#define NROWS  16        // batch rows per WG
#define WDS    68        // Wd col stride (floats): 16B-aligned
#define ZSTR   68        // Zc row stride (floats)

typedef __attribute__((ext_vector_type(8))) short short8;   // 8 bf16 (4 VGPRs)
typedef __attribute__((ext_vector_type(4))) float floatx4;  // MFMA C/D

#define C5 (-7.21347520444481703f)   // -5*log2(e): sigmoid(5z) = rcp(1+exp2(C5*z))

// ---------- helpers ----------

__device__ __forceinline__ unsigned short f2bf(float f) {
    __hip_bfloat16 h = __float2bfloat16(f);
    return __builtin_bit_cast(unsigned short, h);
}
__device__ __forceinline__ unsigned pack2(float a, float b) {
    return (unsigned)f2bf(a) | ((unsigned)f2bf(b) << 16);
}
// sigmoid in folded domain: y = C5*(z+b); sigma = rcp(1+exp2(y)). Overflow exact.
__device__ __forceinline__ float sig2(float y) {
    return __builtin_amdgcn_rcpf(1.0f + __builtin_amdgcn_exp2f(y));
}

// ---------- W fp32 -> bf16 (d_ws re-poisoned every launch, so rerun) ----------
// Workspace usage is EXACTLY NEVAL*NCOLS*2 bytes (proven safe).

__global__ __launch_bounds__(256) void wconv(const float* __restrict__ W,
                                             ushort* __restrict__ Wb, int n8) {
    int i = blockIdx.x * blockDim.x + threadIdx.x;
    if (i < n8) {
        float4 v0 = ((const float4*)W)[2 * i];
        float4 v1 = ((const float4*)W)[2 * i + 1];
        uint4 pk;
        pk.x = pack2(v0.x, v0.y); pk.y = pack2(v0.z, v0.w);
        pk.z = pack2(v1.x, v1.y); pk.w = pack2(v1.z, v1.w);
        ((uint4*)Wb)[i] = pk;
    }
}

// ---------- main kernel ----------
// ROUND-21: chain broadcast LDS->DPP. R20 fixed the spill (WRITE back to
// 4MB) but landed at 183us = 286 cyc/step: the serial path per step was
// sig2 -> ds_bpermute (~120cyc single-outstanding LDS latency) -> weight
// ds_read waits -> fma. Re-map chain lanes 16g+r -> 4r+g: row r's 4 node
// groups live in ONE 4-lane quad, so the owner->all broadcast is a
// quad_perm DPP mov (~2cyc VALU) instead of an LDS round-trip. All 64
// lanes useful (16 rows x 4 groups). Weight reads: 4 distinct b128 addrs
// per wave (2-way bank aliasing = free). Everything else identical to the
// PASSING R20 code (mains, stagers, Zc, Wd, phases).
//   role 0      (1 wave): chain (above); per step J (literal): all lanes
//               sig2 their local elem (J&15), DPP-broadcast from quad-lane
//               J>>4, 4 unguarded quad-fmas (ride-along weights are exact
//               0.0 from strict lower-tri W -> bit-identical).
//   roles 1,2,3,5 (4 waves): mains, node-group ng. Phase 1: tail(k) = 2
//               MFMAs (B prefetched) + Zc^T store. Phase 2: main(k+1) over
//               [0,512+64k) into regs + prefetch tail B(k+1).
//   roles 4,6,7 (3 waves): stagers: Wd[(k+1)&1][j*WDS+i] = C5*W[...].
// Slot: phase1 | beta | phase2 | alpha. Disjoint: mains read O cols
// [0,512+64k); chain writes [512+64k,+64).

// --- chain macros: literal indices only ---
#define QP(g) ((g) | ((g) << 2) | ((g) << 4) | ((g) << 6))
#define CSTEP(J, Q, C, ON) { \
    float sg_ = sig2(vq##Q.C); \
    ON = __builtin_bit_cast(float, \
        __builtin_amdgcn_update_dpp(0, __builtin_bit_cast(int, sg_), \
                                    QP((J) >> 4), 0xF, 0xF, true)); \
    const float* wc_ = wd + (J) * WDS + g16; \
    floatx4 w0_ = *(const floatx4*)(wc_); \
    floatx4 w1_ = *(const floatx4*)(wc_ + 4); \
    floatx4 w2_ = *(const floatx4*)(wc_ + 8); \
    floatx4 w3_ = *(const floatx4*)(wc_ + 12); \
    vq0 = w0_ * ON + vq0; \
    vq1 = w1_ * ON + vq1; \
    vq2 = w2_ * ON + vq2; \
    vq3 = w3_ * ON + vq3; \
}
#define CSTORE(gidx) \
    if ((lane & 3) == 0) { \
        uint4 pk; \
        pk.x = pack2(o0, o1); pk.y = pack2(o2, o3); \
        pk.z = pack2(o4, o5); pk.w = pack2(o6, o7); \
        *(uint4*)&O[(rr << 11) + ((L0 + (gidx) * 8 + (rr << 3)) & 2047)] = pk; \
        if (k >= 20) { \
            float* op = out + ((long)blockIdx.x * NROWS + rr) * NOUT \
                            + (i0 - OUT_BASE) + (gidx) * 8; \
            *(float4*)op       = float4{o0, o1, o2, o3}; \
            *(float4*)(op + 4) = float4{o4, o5, o6, o7}; \
        } \
    }
#define CINIT(Q) { \
    floatx4 zv_ = *(const floatx4*)(zr + (Q) * 4); \
    float4  bv_ = *(const float4*)(bb + (Q) * 4); \
    vq##Q.x = C5 * (zv_.x + bv_.x); \
    vq##Q.y = C5 * (zv_.y + bv_.y); \
    vq##Q.z = C5 * (zv_.z + bv_.z); \
    vq##Q.w = C5 * (zv_.w + bv_.w); \
}
// 16 steps + 2 stores (pattern repeats every 16 steps)
#define CLEAF(B) \
    CSTEP((B)+0,0,x,o0)  CSTEP((B)+1,0,y,o1)  CSTEP((B)+2,0,z,o2)  CSTEP((B)+3,0,w,o3) \
    CSTEP((B)+4,1,x,o4)  CSTEP((B)+5,1,y,o5)  CSTEP((B)+6,1,z,o6)  CSTEP((B)+7,1,w,o7) \
    CSTORE((B)/8) \
    CSTEP((B)+8,2,x,o0)  CSTEP((B)+9,2,y,o1)  CSTEP((B)+10,2,z,o2) CSTEP((B)+11,2,w,o3) \
    CSTEP((B)+12,3,x,o4) CSTEP((B)+13,3,y,o5) CSTEP((B)+14,3,z,o6) CSTEP((B)+15,3,w,o7) \
    CSTORE((B)/8 + 1)

__global__ __launch_bounds__(512, 1) void ffnet(const float* __restrict__ x,
                                                const float* __restrict__ W,
                                                const ushort* __restrict__ Wb,
                                                const float* __restrict__ bias,
                                                float* __restrict__ out) {
    __shared__ unsigned short O[NROWS * 2048];   // 64 KB
    __shared__ float Wd[2][64 * WDS];            // 34.8 KB dbuf diag blocks [j][i], C5-scaled
    __shared__ float Zc[NROWS * ZSTR];           // 4.4 KB  [row][node]

    const int t    = threadIdx.x;
    const int w    = t >> 6;        // wave 0..7
    const int lane = t & 63;

    const int cw   = (int)blockIdx.x & 7;
    const int role = (w - cw) & 7;
    const bool isMain   = (role == 1) | (role == 2) | (role == 3) | (role == 5);
    const bool isStager = (role == 4) | (role == 6) | (role == 7);
    const int ng   = (role >= 5) ? 3 : role - 1;              // valid iff isMain
    const int sidx = (role == 4) ? 0 : ((role == 6) ? 1 : 2); // valid iff isStager
    const int spt  = (sidx << 6) + lane;                      // 0..191

    // MFMA frag roles (mains)
    const int m16  = lane & 15;     // A row (batch row) / D col (node in group)
    const int quad = lane >> 4;
    const int arow = m16 << 11;
    const int arot = m16 << 3;

    // chain roles: lane = 4r + g (row r's 4 node-groups in one DPP quad)
    const int rr   = lane >> 2;            // batch row 0..15
    const int g16  = (lane & 3) << 4;      // node-group base (0,16,32,48)

    // ---- stage x rows into LDS as bf16 (swizzled); 8 waves x 2 rows ----
    #pragma unroll
    for (int r2 = 0; r2 < 2; ++r2) {
        const int rs = w + (r2 << 3);
        const long rowS = (long)blockIdx.x * NROWS + rs;
        const float* xr = x + rowS * NIN + lane * 8;
        float4 v0 = *(const float4*)xr;
        float4 v1 = *(const float4*)(xr + 4);
        uint4 pk;
        pk.x = pack2(v0.x, v0.y); pk.y = pack2(v0.z, v0.w);
        pk.z = pack2(v1.x, v1.y); pk.w = pack2(v1.z, v1.w);
        *(uint4*)&O[(rs << 11) + ((lane * 8 + (rs << 3)) & 2047)] = pk;
    }
    __syncthreads();

    short8 tb0 = {}, tb1 = {};      // prefetched tail B-frags
    floatx4 accM = {0.f, 0.f, 0.f, 0.f};

    // ---- prologue (phase-2-like work for slot 0) ----
    if (isMain) {
        const ushort* wbr = Wb + (size_t)((ng << 4) + m16) * NCOLS;
        #pragma unroll 4
        for (int kk = 0; kk < NIN - BK; kk += 32) {
            short8 a = *(const short8*)&O[arow + ((kk + (quad << 3) + arot) & 2047)];
            short8 b = *(const short8*)&wbr[kk + (quad << 3)];
            accM = __builtin_amdgcn_mfma_f32_16x16x32_bf16(a, b, accM, 0, 0, 0);
        }
        tb0 = *(const short8*)&wbr[(NIN - BK) + (quad << 3)];
        tb1 = *(const short8*)&wbr[(NIN - 32) + (quad << 3)];
    } else if (isStager) {
        // stage Wd[0] for block 0: Wd[j*WDS+i] = C5*W[i][512+j]
        const float* wsrc = W + NIN;
        for (int idx = spt; idx < 4096; idx += 192) {
            const int i = idx >> 6, j = idx & 63;
            Wd[0][j * WDS + i] = C5 * wsrc[(size_t)i * NCOLS + j];
        }
    }

    for (int k = 0; k < NBLK; ++k) {
        const int i0 = k << 6;
        const int L0 = NIN + i0;

        // ===== phase 1: mains: tail(k) + Zc^T store =====
        if (isMain) {
            const int ts = L0 - BK;
            short8 a0 = *(const short8*)&O[arow + ((ts + (quad << 3) + arot) & 2047)];
            accM = __builtin_amdgcn_mfma_f32_16x16x32_bf16(a0, tb0, accM, 0, 0, 0);
            short8 a1 = *(const short8*)&O[arow + ((ts + 32 + (quad << 3) + arot) & 2047)];
            accM = __builtin_amdgcn_mfma_f32_16x16x32_bf16(a1, tb1, accM, 0, 0, 0);
            // D: lane q*16+n holds z[row 4q+p][node 16ng+n]
            const int n = (ng << 4) + m16;
            #pragma unroll
            for (int p = 0; p < 4; ++p)
                Zc[((quad << 2) + p) * ZSTR + n] = accM[p];
        }
        __syncthreads();            // beta: Zc(k) + Wd(k) visible

        if (role == 0) {
            // ===== chain: block k, 64 static steps, state in 4 quads =====
            floatx4 vq0, vq1, vq2, vq3;
            {
                const float* zr = &Zc[rr * ZSTR + g16];
                const float* bb = bias + i0 + g16;
                CINIT(0) CINIT(1) CINIT(2) CINIT(3)
            }
            const float* wd = &Wd[k & 1][0];
            float o0, o1, o2, o3, o4, o5, o6, o7;
            CLEAF(0)
            CLEAF(16)
            CLEAF(32)
            CLEAF(48)
        } else if (isMain && k + 1 < NBLK) {
            // ===== mains: main(k+1) over [0, 512+64k) + tail-B prefetch =====
            const int b = k + 1;
            const ushort* wbr = Wb + (size_t)((b << 6) + (ng << 4) + m16) * NCOLS;
            const int ts = NIN + (b << 6) - BK;
            tb0 = *(const short8*)&wbr[ts + (quad << 3)];
            tb1 = *(const short8*)&wbr[ts + 32 + (quad << 3)];
            floatx4 z = {0.f, 0.f, 0.f, 0.f};
            const int hi = NIN + i0;
            #pragma unroll 4
            for (int kk = 0; kk < hi; kk += 32) {
                short8 a  = *(const short8*)&O[arow + ((kk + (quad << 3) + arot) & 2047)];
                short8 bf = *(const short8*)&wbr[kk + (quad << 3)];
                z = __builtin_amdgcn_mfma_f32_16x16x32_bf16(a, bf, z, 0, 0, 0);
            }
            accM = z;
        } else if (isStager && k + 1 < NBLK) {
            // ===== stagers: Wd[(k+1)&1] = C5 * diag-block(k+1), transposed =====
            const int b = k + 1;
            float* wdn = &Wd[b & 1][0];
            const float* wsrc = W + (size_t)(b << 6) * NCOLS + (NIN + (b << 6));
            for (int idx = spt; idx < 4096; idx += 192) {
                const int i = idx >> 6, j = idx & 63;
                wdn[j * WDS + i] = C5 * wsrc[(size_t)i * NCOLS + j];
            }
        }
        __syncthreads();            // alpha: O(k) visible; Zc/Wd consumed
    }
}

// ---------- launch ----------

extern "C" void kernel_launch(void* const* d_in, const int* in_sizes, int n_in,
                              void* d_out, int out_size, void* d_ws, size_t ws_size,
                              hipStream_t stream) {
    const float* x  = (const float*)d_in[0];   // [4096, 512]
    const float* W  = (const float*)d_in[1];   // [1536, 2048]
    const float* b  = (const float*)d_in[2];   // [1536]
    float* out = (float*)d_out;                // [4096, 256]
    ushort* Wb = (ushort*)d_ws;                // bf16 W copy (6.29 MB, exact proven usage)

    int n8 = NEVAL * NCOLS / 8;
    wconv<<<n8 / 256, 256, 0, stream>>>(W, Wb, n8);
    ffnet<<<4096 / NROWS, 512, 0, stream>>>(x, W, Wb, b, out);
}